// Round 6
// baseline (418.943 us; speedup 1.0000x reference)
//
#include <hip/hip_runtime.h>
#include <math.h>

#define HID   1024
#define NHEAD 16
#define DHEAD 64
#define BATCH 2
#define SEQ   2048

#define TQ   64
#define TK2  128
#define NW2  191     // TQ+TK2-1 rel-shift band rows
#define LDP  136     // P stride (bf16 elems)
#define LDBT 68      // bandT stride: band[l][i'], i' in 0..64, +3 pad

#define KSPLIT 2048  // K' = 2*HID (hi/lo interleaved)
#define HEADSZ ((size_t)BATCH * SEQ * HID)

typedef __bf16 bf16_t;
typedef bf16_t bf16x8 __attribute__((ext_vector_type(8)));
typedef bf16_t bf16x4 __attribute__((ext_vector_type(4)));
typedef float  f32x4  __attribute__((ext_vector_type(4)));

__device__ __forceinline__ void load_lds16(const void* g, void* l) {
    __builtin_amdgcn_global_load_lds(
        (const __attribute__((address_space(1))) unsigned int*)g,
        (__attribute__((address_space(3))) unsigned int*)l, 16, 0, 0);
}

__device__ __forceinline__ void split2(float x, bf16_t* hi, bf16_t* lo) {
    bf16_t h = (bf16_t)x;
    *hi = h;
    *lo = (bf16_t)(x - (float)h);
}

// ---------------- prep 1: fp32 [M][1024] -> hi/lo-interleaved bf16 [M][2048]
__global__ __launch_bounds__(256) void split_interleave(
    const float* __restrict__ in, bf16_t* __restrict__ out, int n4)
{
    int g = blockIdx.x * 256 + threadIdx.x;
    if (g >= n4) return;
    float4 v = ((const float4*)in)[g];
    int m = g >> 8, c4 = g & 255;
    float xs[4] = {v.x, v.y, v.z, v.w};
    bf16x8 o;
#pragma unroll
    for (int e = 0; e < 4; e++) {
        bf16_t h, l; split2(xs[e], &h, &l);
        o[2 * e] = h; o[2 * e + 1] = l;
    }
    *(bf16x8*)(out + (size_t)m * KSPLIT + c4 * 8) = o;
}

// ---------------- prep 2: W fp32 [1024 k][1024 n] -> Wt' bf16 [1024 n][2048 k']
// 3 weights in one launch (blockIdx.z selects)
__global__ __launch_bounds__(256) void transpose_split3(
    const float* __restrict__ W0, const float* __restrict__ W1,
    const float* __restrict__ W2, bf16_t* __restrict__ WtBase)
{
    __shared__ float t[64][65];
    const int z = blockIdx.z;
    const float* W = (z == 0) ? W0 : (z == 1) ? W1 : W2;
    bf16_t* Wt = WtBase + (size_t)z * 1024 * KSPLIT;
    const int tid = threadIdx.x;
    const int n0 = blockIdx.x * 64, k0 = blockIdx.y * 64;
    for (int idx = tid; idx < 1024; idx += 256) {
        int r = idx >> 4, c4 = (idx & 15) * 4;
        float4 v = *(const float4*)(W + (size_t)(k0 + r) * HID + n0 + c4);
        t[r][c4] = v.x; t[r][c4 + 1] = v.y; t[r][c4 + 2] = v.z; t[r][c4 + 3] = v.w;
    }
    __syncthreads();
    for (int idx = tid; idx < 1024; idx += 256) {
        int nr = idx >> 4, c4 = (idx & 15) * 4;
        bf16x8 o;
#pragma unroll
        for (int e = 0; e < 4; e++) {
            bf16_t h, l; split2(t[c4 + e][nr], &h, &l);
            o[2 * e] = h; o[2 * e + 1] = l;
        }
        *(bf16x8*)(Wt + (size_t)(n0 + nr) * KSPLIT + (k0 + c4) * 2) = o;
    }
}

__global__ __launch_bounds__(256) void transpose_split(
    const float* __restrict__ W, bf16_t* __restrict__ Wt)
{
    __shared__ float t[64][65];
    const int tid = threadIdx.x;
    const int n0 = blockIdx.x * 64, k0 = blockIdx.y * 64;
    for (int idx = tid; idx < 1024; idx += 256) {
        int r = idx >> 4, c4 = (idx & 15) * 4;
        float4 v = *(const float4*)(W + (size_t)(k0 + r) * HID + n0 + c4);
        t[r][c4] = v.x; t[r][c4 + 1] = v.y; t[r][c4 + 2] = v.z; t[r][c4 + 3] = v.w;
    }
    __syncthreads();
    for (int idx = tid; idx < 1024; idx += 256) {
        int nr = idx >> 4, c4 = (idx & 15) * 4;
        bf16x8 o;
#pragma unroll
        for (int e = 0; e < 4; e++) {
            bf16_t h, l; split2(t[c4 + e][nr], &h, &l);
            o[2 * e] = h; o[2 * e + 1] = l;
        }
        *(bf16x8*)(Wt + (size_t)(n0 + nr) * KSPLIT + (k0 + c4) * 2) = o;
    }
}

// ---------------- fused QKV split-bf16 MFMA GEMM ----------------------------
__global__ __launch_bounds__(256, 3) void gemm_qkv_fused(
    const bf16_t* __restrict__ A, const bf16_t* __restrict__ Wt3,
    const float* __restrict__ bq, const float* __restrict__ bk,
    const float* __restrict__ bv, const float* __restrict__ rrb,
    bf16_t* __restrict__ Cq)
{
    __shared__ bf16_t As[128 * 64];
    __shared__ bf16_t Bs[128 * 64];
    const int tid = threadIdx.x;
    const int w = tid >> 6, lane = tid & 63;
    const int quad = lane >> 4, l16 = lane & 15;
    const int bn = blockIdx.x * 128;
    const int bm = blockIdx.y * 128;
    const int proj = bn >> 10;
    const int vswap = (proj == 2);

    const int srow = tid >> 3;
    const int scg  = (tid & 7) ^ ((tid >> 3) & 7);
    const bf16_t* Ab = A   + (size_t)(bm + srow) * KSPLIT + scg * 8;
    const bf16_t* Bb = Wt3 + (size_t)(bn + srow) * KSPLIT + scg * 8;

    f32x4 acc[2][8];
#pragma unroll
    for (int i = 0; i < 2; i++)
#pragma unroll
        for (int j = 0; j < 8; j++) {
            acc[i][j][0] = 0.f; acc[i][j][1] = 0.f;
            acc[i][j][2] = 0.f; acc[i][j][3] = 0.f;
        }

    const bf16_t* P1 = vswap ? Bs : As;
    const bf16_t* P2 = vswap ? As : Bs;

    for (int k0 = 0; k0 < KSPLIT; k0 += 64) {
#pragma unroll
        for (int j = 0; j < 4; j++) {
            load_lds16(Ab + (size_t)j * 32 * KSPLIT + k0, &As[j * 2048 + w * 512]);
            load_lds16(Bb + (size_t)j * 32 * KSPLIT + k0, &Bs[j * 2048 + w * 512]);
        }
        __syncthreads();
        bf16x8 af[2][2];
#pragma unroll
        for (int mt = 0; mt < 2; mt++) {
            int r = w * 32 + mt * 16 + l16, rx = r & 7;
            int c0 = (quad ^ rx);
            af[mt][0] = *(const bf16x8*)&P1[r * 64 + c0 * 8];
            af[mt][1] = *(const bf16x8*)&P1[r * 64 + (c0 ^ 4) * 8];
        }
#pragma unroll
        for (int nt = 0; nt < 8; nt++) {
            int r = nt * 16 + l16, rx = r & 7;
            int c0 = (quad ^ rx);
            bf16x8 b0 = *(const bf16x8*)&P2[r * 64 + c0 * 8];
            bf16x8 b1 = *(const bf16x8*)&P2[r * 64 + (c0 ^ 4) * 8];
#pragma unroll
            for (int mt = 0; mt < 2; mt++) {
                acc[mt][nt] = __builtin_amdgcn_mfma_f32_16x16x32_bf16(af[mt][0], b0, acc[mt][nt], 0, 0, 0);
                acc[mt][nt] = __builtin_amdgcn_mfma_f32_16x16x32_bf16(af[mt][1], b1, acc[mt][nt], 0, 0, 0);
            }
        }
        __syncthreads();
    }

#pragma unroll
    for (int mt = 0; mt < 2; mt++)
#pragma unroll
        for (int nt = 0; nt < 8; nt++)
#pragma unroll
            for (int r4 = 0; r4 < 4; r4++) {
                int rowp = w * 32 + mt * 16 + quad * 4 + r4;
                int colp = nt * 16 + l16;
                float v = acc[mt][nt][r4];
                if (!vswap) {
                    int m = bm + rowp, nloc = (bn & 1023) + colp;
                    v += (proj == 0) ? (bq[nloc] + rrb[nloc]) : bk[nloc];
                    int bb = m >> 11, s = m & (SEQ - 1);
                    int nh = nloc >> 6, d = nloc & 63;
                    Cq[(size_t)proj * HEADSZ + (((size_t)(bb * NHEAD + nh) * SEQ + s) * DHEAD) + d] = (bf16_t)v;
                } else {
                    int nloc = (bn & 1023) + rowp, m = bm + colp;
                    v += bv[nloc];
                    int bb = m >> 11, s = m & (SEQ - 1);
                    int nh = nloc >> 6, d = nloc & 63;
                    Cq[(size_t)2 * HEADSZ + (((size_t)(bb * NHEAD + nh) * DHEAD + d) * SEQ) + s] = (bf16_t)v;
                }
            }
}

// ---------------- R projection (single, row layout) -------------------------
__global__ __launch_bounds__(256, 3) void gemm_split_mfma(
    const bf16_t* __restrict__ A, const bf16_t* __restrict__ Bw,
    bf16_t* __restrict__ C)
{
    __shared__ bf16_t As[128 * 64];
    __shared__ bf16_t Bs[128 * 64];
    const int tid = threadIdx.x;
    const int w = tid >> 6, lane = tid & 63;
    const int quad = lane >> 4, l16 = lane & 15;
    const int bn = blockIdx.x * 128;
    const int bm = blockIdx.y * 128;
    const int srow = tid >> 3;
    const int scg  = (tid & 7) ^ ((tid >> 3) & 7);
    const bf16_t* Ab = A  + (size_t)(bm + srow) * KSPLIT + scg * 8;
    const bf16_t* Bb = Bw + (size_t)(bn + srow) * KSPLIT + scg * 8;

    f32x4 acc[2][8];
#pragma unroll
    for (int i = 0; i < 2; i++)
#pragma unroll
        for (int j = 0; j < 8; j++) {
            acc[i][j][0] = 0.f; acc[i][j][1] = 0.f;
            acc[i][j][2] = 0.f; acc[i][j][3] = 0.f;
        }

    for (int k0 = 0; k0 < KSPLIT; k0 += 64) {
#pragma unroll
        for (int j = 0; j < 4; j++) {
            load_lds16(Ab + (size_t)j * 32 * KSPLIT + k0, &As[j * 2048 + w * 512]);
            load_lds16(Bb + (size_t)j * 32 * KSPLIT + k0, &Bs[j * 2048 + w * 512]);
        }
        __syncthreads();
        bf16x8 af[2][2];
#pragma unroll
        for (int mt = 0; mt < 2; mt++) {
            int r = w * 32 + mt * 16 + l16, rx = r & 7;
            int c0 = (quad ^ rx);
            af[mt][0] = *(const bf16x8*)&As[r * 64 + c0 * 8];
            af[mt][1] = *(const bf16x8*)&As[r * 64 + (c0 ^ 4) * 8];
        }
#pragma unroll
        for (int nt = 0; nt < 8; nt++) {
            int r = nt * 16 + l16, rx = r & 7;
            int c0 = (quad ^ rx);
            bf16x8 b0 = *(const bf16x8*)&Bs[r * 64 + c0 * 8];
            bf16x8 b1 = *(const bf16x8*)&Bs[r * 64 + (c0 ^ 4) * 8];
#pragma unroll
            for (int mt = 0; mt < 2; mt++) {
                acc[mt][nt] = __builtin_amdgcn_mfma_f32_16x16x32_bf16(af[mt][0], b0, acc[mt][nt], 0, 0, 0);
                acc[mt][nt] = __builtin_amdgcn_mfma_f32_16x16x32_bf16(af[mt][1], b1, acc[mt][nt], 0, 0, 0);
            }
        }
        __syncthreads();
    }
#pragma unroll
    for (int mt = 0; mt < 2; mt++)
#pragma unroll
        for (int nt = 0; nt < 8; nt++)
#pragma unroll
            for (int r4 = 0; r4 < 4; r4++) {
                int rowp = w * 32 + mt * 16 + quad * 4 + r4;
                int colp = nt * 16 + l16;
                int s = bm + rowp, n = bn + colp;
                int nh = n >> 6, d = n & 63;
                C[(((size_t)nh * SEQ + s) * DHEAD) + d] = (bf16_t)acc[mt][nt][r4];
            }
}

// ---------------- prep 3: dcorr[b,n,s] = (rwb-rrb) . K[b,n,s,:] -------------
__global__ __launch_bounds__(256) void dcorr_kernel(
    const bf16_t* __restrict__ Kh, const float* __restrict__ rwb,
    const float* __restrict__ rrb, float* __restrict__ dc)
{
    int g = blockIdx.x * 256 + threadIdx.x;
    int bn = g >> 11;
    int n = bn & (NHEAD - 1);
    const bf16_t* kr = Kh + (size_t)g * DHEAD;
    float a = 0.f;
#pragma unroll
    for (int c8 = 0; c8 < 8; c8++) {
        bf16x8 kv = *(const bf16x8*)(kr + c8 * 8);
#pragma unroll
        for (int e = 0; e < 8; e++) {
            int d = c8 * 8 + e;
            a = fmaf(rwb[n * DHEAD + d] - rrb[n * DHEAD + d], (float)kv[e], a);
        }
    }
    dc[g] = a;
}

// ---------------- MFMA flash rel-attention v4 --------------------------------
// Case-uniform fast path: lstar = 64+i0-j0. lstar<=0 -> all case-2 (shifted
// A-frags qs[rq+1], band value == score band directly); lstar>=191 -> all
// case-1. Uniform tiles: no bd64 dot, trivial gather addressing, 3 barriers.
// Mixed tiles (1-2 per block): round-5 slow path, 4 barriers.
__global__ __launch_bounds__(256, 2) void rel_attn_mfma4(
    const bf16_t* __restrict__ Qh, const bf16_t* __restrict__ Kh,
    const bf16_t* __restrict__ Vth, const bf16_t* __restrict__ Rkh,
    const float* __restrict__ dcorr, const bf16_t* __restrict__ zp,
    float* __restrict__ Out)
{
    __shared__ bf16_t qs[65 * 64];      // swizzled, stride 64
    __shared__ bf16_t ktP[64 * LDP];    // kt[128*64] U P[64*136]
    __shared__ bf16_t vt[64 * 128];     // [d][key], swizzled (mask 15)
    __shared__ bf16_t rkb[192 * LDBT];  // rkc[192*64] U bandT[192*68]
    __shared__ float dco[TK2];

    const int tid = threadIdx.x;
    const int w = tid >> 6, lane = tid & 63;
    const int quad = lane >> 4, l16 = lane & 15;
    const int i0 = blockIdx.x * TQ;
    const int n = blockIdx.y, b = blockIdx.z;

    const bf16_t* Qb = Qh + ((size_t)(b * NHEAD + n) * SEQ + i0) * DHEAD;
    const bf16_t* Kb = Kh + (size_t)(b * NHEAD + n) * SEQ * DHEAD;
    const bf16_t* Vb = Vth + (size_t)(b * NHEAD + n) * DHEAD * SEQ;
    const bf16_t* Rb = Rkh + (size_t)n * SEQ * DHEAD;
    const float*  Db = dcorr + (size_t)(b * NHEAD + n) * SEQ;

    // stage qs (rows i0..i0+64; row 64 zero if OOB), source-chunk swizzle
    for (int idx = tid; idx < 65 * 8; idx += 256) {
        int row = idx >> 3, p = idx & 7;
        int g = p ^ (row & 7);
        uint4 val = make_uint4(0, 0, 0, 0);
        if (i0 + row < SEQ) val = *(const uint4*)(Qb + row * DHEAD + g * 8);
        *(uint4*)&qs[row * 64 + p * 8] = val;
    }
    __syncthreads();

    // hoisted A-fragments: rows rq (case-1) and rq+1 (uniform case-2)
    const int rq = 16 * w + l16;
    const int cq0 = quad ^ (rq & 7);
    const bf16x8 aq0 = *(const bf16x8*)&qs[rq * 64 + cq0 * 8];
    const bf16x8 aq1 = *(const bf16x8*)&qs[rq * 64 + (cq0 ^ 4) * 8];
    const int rq1 = rq + 1;
    const int cq1 = quad ^ (rq1 & 7);
    const bf16x8 as0 = *(const bf16x8*)&qs[rq1 * 64 + cq1 * 8];
    const bf16x8 as1 = *(const bf16x8*)&qs[rq1 * 64 + (cq1 ^ 4) * 8];

    f32x4 o[4];
    float mprev[4], lsum[4];
#pragma unroll
    for (int t = 0; t < 4; t++) {
        o[t][0] = 0.f; o[t][1] = 0.f; o[t][2] = 0.f; o[t][3] = 0.f;
        mprev[t] = -3.0e38f; lsum[t] = 0.f;
    }
    const float C1 = 0.18033688f;   // 0.125 * log2(e)

    for (int j0 = 0; j0 < SEQ; j0 += TK2) {
        const int lstar = 64 + i0 - j0;            // rr == SEQ at l == lstar
        const bool uc2 = (lstar <= 0);
        const bool mixed = (lstar > 0) && (lstar < NW2);

        __syncthreads();                             // B1: prev consumers done
#pragma unroll
        for (int t = 0; t < 4; t++) {
            int r0 = (w + 4 * t) * 8;
            int row = r0 + (lane >> 3);
            int gch = (lane & 7) ^ (row & 7);
            load_lds16(Kb + (size_t)(j0 + row) * DHEAD + gch * 8, &ktP[r0 * 64]);
        }
#pragma unroll
        for (int t = 0; t < 4; t++) {
            int d0 = (w + 4 * t) * 4;
            int d = d0 + (lane >> 4);
            int gch = (lane & 15) ^ (d & 15);
            load_lds16(Vb + (size_t)d * SEQ + j0 + gch * 8, &vt[d0 * 128]);
        }
        const int base1 = SEQ + j0 - i0 - TQ;
#pragma unroll
        for (int t = 0; t < 6; t++) {
            int l0 = (w + 4 * t) * 8;
            int l = l0 + (lane >> 3);
            int rr = base1 + l;
            const bf16_t* rp = (rr < SEQ) ? (Rb + (size_t)rr * DHEAD)
                             : (rr > SEQ) ? (Rb + (size_t)(rr - SEQ - 1) * DHEAD) : zp;
            int gch = (lane & 7) ^ (l & 7);
            load_lds16(rp + gch * 8, &rkb[l0 * 64]);
        }
        if (tid < 32) load_lds16(Db + j0 + tid * 4, dco);
        __syncthreads();                             // B2: staging visible

        // ---- MFMA: AC (8x2) + band (12x2) ----
        f32x4 sac[8];
#pragma unroll
        for (int nt = 0; nt < 8; nt++) {
            int r = nt * 16 + l16;
            int c0 = quad ^ (r & 7);
            bf16x8 b0 = *(const bf16x8*)&ktP[r * 64 + c0 * 8];
            bf16x8 b1 = *(const bf16x8*)&ktP[r * 64 + (c0 ^ 4) * 8];
            f32x4 c; c[0] = 0.f; c[1] = 0.f; c[2] = 0.f; c[3] = 0.f;
            c = __builtin_amdgcn_mfma_f32_16x16x32_bf16(aq0, b0, c, 0, 0, 0);
            c = __builtin_amdgcn_mfma_f32_16x16x32_bf16(aq1, b1, c, 0, 0, 0);
            sac[nt] = c;
        }
        const bf16x8 ba0 = uc2 ? as0 : aq0;   // wave-uniform select
        const bf16x8 ba1 = uc2 ? as1 : aq1;
        f32x4 bdc[12];
#pragma unroll
        for (int lt = 0; lt < 12; lt++) {
            int l = lt * 16 + l16;
            int c0 = quad ^ (l & 7);
            bf16x8 b0 = *(const bf16x8*)&rkb[l * 64 + c0 * 8];
            bf16x8 b1 = *(const bf16x8*)&rkb[l * 64 + (c0 ^ 4) * 8];
            f32x4 c; c[0] = 0.f; c[1] = 0.f; c[2] = 0.f; c[3] = 0.f;
            c = __builtin_amdgcn_mfma_f32_16x16x32_bf16(ba0, b0, c, 0, 0, 0);
            c = __builtin_amdgcn_mfma_f32_16x16x32_bf16(ba1, b1, c, 0, 0, 0);
            bdc[lt] = c;
        }
        // band row-64 (case-2 source for il=63): mixed tiles only
        float bd64 = 0.f;
        if (mixed && w >= 2) {
            int l = (w - 2) * 64 + lane;
            int lx = l & 7;
#pragma unroll
            for (int c = 0; c < 8; c++) {
                bf16x8 qv = *(const bf16x8*)&qs[64 * 64 + c * 8];
                bf16x8 rv = *(const bf16x8*)&rkb[l * 64 + (c ^ lx) * 8];
#pragma unroll
                for (int e = 0; e < 8; e++) bd64 = fmaf((float)qv[e], (float)rv[e], bd64);
            }
        }
        __syncthreads();                             // B3: kt/rkc frag reads done

        // ---- band store, transposed: bandT[l][i'] (b64 writes) ----
#pragma unroll
        for (int lt = 0; lt < 12; lt++) {
            int l = lt * 16 + l16;
            bf16x4 pk;
#pragma unroll
            for (int r = 0; r < 4; r++) pk[r] = (bf16_t)bdc[lt][r];
            *(bf16x4*)&rkb[l * LDBT + 16 * w + quad * 4] = pk;
        }
        if (mixed) {
            if (w >= 2) rkb[((w - 2) * 64 + lane) * LDBT + 64] = (bf16_t)bd64;
            __syncthreads();                         // B4: band visible (cross-wave)
        }

        // ---- gather + assemble + online softmax (exp2) ----
        float sv[8][4];
        if (mixed) {
#pragma unroll
            for (int nt = 0; nt < 8; nt++) {
                float dcv = dco[nt * 16 + l16];
#pragma unroll
                for (int r = 0; r < 4; r++) {
                    int il = 16 * w + quad * 4 + r;
                    int jl = nt * 16 + l16;
                    int l = jl + (TQ - 1) - il;
                    int rr = base1 + l;
                    int ip = il + (rr > SEQ ? 1 : 0);
                    float bd = (float)rkb[l * LDBT + ip];
                    sv[nt][r] = sac[nt][r] + dcv + bd;
                }
            }
        } else {
            const int il0 = 16 * w + quad * 4;
            const int lb = l16 + (TQ - 1) - il0;     // l at r=0, nt=0
#pragma unroll
            for (int nt = 0; nt < 8; nt++) {
                float dcv = dco[nt * 16 + l16];
#pragma unroll
                for (int r = 0; r < 4; r++) {
                    float bd = (float)rkb[(lb + nt * 16 - r) * LDBT + il0 + r];
                    sv[nt][r] = sac[nt][r] + dcv + bd;
                }
            }
        }
#pragma unroll
        for (int r = 0; r < 4; r++) {
            float m = sv[0][r];
#pragma unroll
            for (int nt = 1; nt < 8; nt++) m = fmaxf(m, sv[nt][r]);
            m = fmaxf(m, __shfl_xor(m, 1));
            m = fmaxf(m, __shfl_xor(m, 2));
            m = fmaxf(m, __shfl_xor(m, 4));
            m = fmaxf(m, __shfl_xor(m, 8));
            float mnew = fmaxf(mprev[r], m);
            float alpha = exp2f((mprev[r] - mnew) * C1);
            float s = 0.f;
#pragma unroll
            for (int nt = 0; nt < 8; nt++) {
                sv[nt][r] = exp2f((sv[nt][r] - mnew) * C1);
                s += sv[nt][r];
            }
            s += __shfl_xor(s, 1); s += __shfl_xor(s, 2);
            s += __shfl_xor(s, 4); s += __shfl_xor(s, 8);
            lsum[r] = lsum[r] * alpha + s;
            mprev[r] = mnew;
#pragma unroll
            for (int nt = 0; nt < 4; nt++) o[nt][r] *= alpha;
        }

        // ---- P store (kt region; reads done at B3; rows wave-local) ----
#pragma unroll
        for (int nt = 0; nt < 8; nt++)
#pragma unroll
            for (int r = 0; r < 4; r++)
                ktP[(16 * w + quad * 4 + r) * LDP + nt * 16 + l16] = (bf16_t)sv[nt][r];

        // ---- PV (wave-local P rows, no barrier) ----
        bf16x8 pa[4];
#pragma unroll
        for (int c = 0; c < 4; c++)
            pa[c] = *(const bf16x8*)&ktP[(16 * w + l16) * LDP + c * 32 + quad * 8];
#pragma unroll
        for (int nt = 0; nt < 4; nt++) {
#pragma unroll
            for (int c = 0; c < 4; c++) {
                int dv = nt * 16 + l16;
                int gch = (4 * c + quad) ^ (dv & 15);
                bf16x8 vb = *(const bf16x8*)&vt[dv * 128 + gch * 8];
                o[nt] = __builtin_amdgcn_mfma_f32_16x16x32_bf16(pa[c], vb, o[nt], 0, 0, 0);
            }
        }
    }

    float inv[4];
#pragma unroll
    for (int r = 0; r < 4; r++) inv[r] = 1.f / lsum[r];
#pragma unroll
    for (int nt = 0; nt < 4; nt++)
#pragma unroll
        for (int r = 0; r < 4; r++) {
            int gi = i0 + 16 * w + quad * 4 + r;
            Out[(size_t)(b * SEQ + gi) * HID + n * DHEAD + nt * 16 + l16] = o[nt][r] * inv[r];
        }
}

extern "C" void kernel_launch(void* const* d_in, const int* in_sizes, int n_in,
                              void* d_out, int out_size, void* d_ws, size_t ws_size,
                              hipStream_t stream) {
    const float* hs  = (const float*)d_in[0];
    const float* r   = (const float*)d_in[1];
    const float* rwb = (const float*)d_in[2];
    const float* rrb = (const float*)d_in[3];
    const float* Wq  = (const float*)d_in[4];
    const float* bq  = (const float*)d_in[5];
    const float* Wk  = (const float*)d_in[6];
    const float* bk  = (const float*)d_in[7];
    const float* Wv  = (const float*)d_in[8];
    const float* bv  = (const float*)d_in[9];
    const float* Wr  = (const float*)d_in[10];

    bf16_t* ws0 = (bf16_t*)d_ws;
    bf16_t* hsS = ws0;
    bf16_t* Wt3 = ws0 + (size_t)4096 * KSPLIT;
    bf16_t* Qh  = Wt3 + (size_t)3072 * KSPLIT;
    bf16_t* Kh  = Qh + HEADSZ;
    bf16_t* Vh  = Kh + HEADSZ;
    bf16_t* Rh  = Vh + HEADSZ;
    bf16_t* rS  = ws0;                                    // reuses hsS region
    bf16_t* WtR = ws0 + (size_t)2048 * KSPLIT;            // reuses hsS region
    float*  dcG = (float*)(ws0 + (size_t)3072 * KSPLIT);  // reuses hsS region
    bf16_t* zp  = ws0 + (size_t)3072 * KSPLIT + 2 * BATCH * NHEAD * SEQ;

    dim3 blk(256);

    split_interleave<<<4096, blk, 0, stream>>>(hs, hsS, (BATCH * SEQ * HID) / 4);
    transpose_split3<<<dim3(16, 16, 3), blk, 0, stream>>>(Wq, Wk, Wv, Wt3);
    gemm_qkv_fused<<<dim3(24, 32), blk, 0, stream>>>(hsS, Wt3, bq, bk, bv, rrb, Qh);

    split_interleave<<<2048, blk, 0, stream>>>(r, rS, (SEQ * HID) / 4);
    transpose_split<<<dim3(16, 16), blk, 0, stream>>>(Wr, WtR);
    gemm_split_mfma<<<dim3(8, 16), blk, 0, stream>>>(rS, WtR, Rh);

    dcorr_kernel<<<(BATCH * NHEAD * SEQ) / 256, blk, 0, stream>>>(Kh, rwb, rrb, dcG);
    hipMemsetAsync(zp, 0, 256, stream);

    rel_attn_mfma4<<<dim3(SEQ / TQ, NHEAD, BATCH), blk, 0, stream>>>(
        Qh, Kh, Vh, Rh, dcG, zp, (float*)d_out);
}

// Round 7
// 393.620 us; speedup vs baseline: 1.0643x; 1.0643x over previous
//
#include <hip/hip_runtime.h>
#include <math.h>

#define HID   1024
#define NHEAD 16
#define DHEAD 64
#define BATCH 2
#define SEQ   2048

#define TQ   64
#define TK2  128
#define NW2  191     // TQ+TK2-1 rel-shift band rows
#define LDP  136     // P stride (bf16 elems)
#define LDBT 68      // bandT stride: band[l][i'], i' in 0..64, +3 pad

#define KSPLIT 2048  // K' = 2*HID (hi/lo interleaved)
#define HEADSZ ((size_t)BATCH * SEQ * HID)

typedef __bf16 bf16_t;
typedef bf16_t bf16x8 __attribute__((ext_vector_type(8)));
typedef bf16_t bf16x4 __attribute__((ext_vector_type(4)));
typedef float  f32x4  __attribute__((ext_vector_type(4)));

__device__ __forceinline__ void load_lds16(const void* g, void* l) {
    __builtin_amdgcn_global_load_lds(
        (const __attribute__((address_space(1))) unsigned int*)g,
        (__attribute__((address_space(3))) unsigned int*)l, 16, 0, 0);
}

__device__ __forceinline__ void split2(float x, bf16_t* hi, bf16_t* lo) {
    bf16_t h = (bf16_t)x;
    *hi = h;
    *lo = (bf16_t)(x - (float)h);
}

// ---------------- prep 1: fp32 [M][1024] -> hi/lo-interleaved bf16 [M][2048]
__global__ __launch_bounds__(256) void split_interleave(
    const float* __restrict__ in, bf16_t* __restrict__ out, int n4)
{
    int g = blockIdx.x * 256 + threadIdx.x;
    if (g >= n4) return;
    float4 v = ((const float4*)in)[g];
    int m = g >> 8, c4 = g & 255;
    float xs[4] = {v.x, v.y, v.z, v.w};
    bf16x8 o;
#pragma unroll
    for (int e = 0; e < 4; e++) {
        bf16_t h, l; split2(xs[e], &h, &l);
        o[2 * e] = h; o[2 * e + 1] = l;
    }
    *(bf16x8*)(out + (size_t)m * KSPLIT + c4 * 8) = o;
}

// ---------------- prep 2: W fp32 [1024 k][1024 n] -> Wt' bf16 [1024 n][2048 k']
__global__ __launch_bounds__(256) void transpose_split3(
    const float* __restrict__ W0, const float* __restrict__ W1,
    const float* __restrict__ W2, bf16_t* __restrict__ WtBase)
{
    __shared__ float t[64][65];
    const int z = blockIdx.z;
    const float* W = (z == 0) ? W0 : (z == 1) ? W1 : W2;
    bf16_t* Wt = WtBase + (size_t)z * 1024 * KSPLIT;
    const int tid = threadIdx.x;
    const int n0 = blockIdx.x * 64, k0 = blockIdx.y * 64;
    for (int idx = tid; idx < 1024; idx += 256) {
        int r = idx >> 4, c4 = (idx & 15) * 4;
        float4 v = *(const float4*)(W + (size_t)(k0 + r) * HID + n0 + c4);
        t[r][c4] = v.x; t[r][c4 + 1] = v.y; t[r][c4 + 2] = v.z; t[r][c4 + 3] = v.w;
    }
    __syncthreads();
    for (int idx = tid; idx < 1024; idx += 256) {
        int nr = idx >> 4, c4 = (idx & 15) * 4;
        bf16x8 o;
#pragma unroll
        for (int e = 0; e < 4; e++) {
            bf16_t h, l; split2(t[c4 + e][nr], &h, &l);
            o[2 * e] = h; o[2 * e + 1] = l;
        }
        *(bf16x8*)(Wt + (size_t)(n0 + nr) * KSPLIT + (k0 + c4) * 2) = o;
    }
}

__global__ __launch_bounds__(256) void transpose_split(
    const float* __restrict__ W, bf16_t* __restrict__ Wt)
{
    __shared__ float t[64][65];
    const int tid = threadIdx.x;
    const int n0 = blockIdx.x * 64, k0 = blockIdx.y * 64;
    for (int idx = tid; idx < 1024; idx += 256) {
        int r = idx >> 4, c4 = (idx & 15) * 4;
        float4 v = *(const float4*)(W + (size_t)(k0 + r) * HID + n0 + c4);
        t[r][c4] = v.x; t[r][c4 + 1] = v.y; t[r][c4 + 2] = v.z; t[r][c4 + 3] = v.w;
    }
    __syncthreads();
    for (int idx = tid; idx < 1024; idx += 256) {
        int nr = idx >> 4, c4 = (idx & 15) * 4;
        bf16x8 o;
#pragma unroll
        for (int e = 0; e < 4; e++) {
            bf16_t h, l; split2(t[c4 + e][nr], &h, &l);
            o[2 * e] = h; o[2 * e + 1] = l;
        }
        *(bf16x8*)(Wt + (size_t)(n0 + nr) * KSPLIT + (k0 + c4) * 2) = o;
    }
}

// ---------------- fused QKV split-bf16 MFMA GEMM ----------------------------
// proj 0=Q (+bq+rrb), 1=K, 2=V (operand swap -> [d][s'] with key-permutation
// p=(j&15)*8+(j>>4) within each 128-key group, matching attention P layout).
__global__ __launch_bounds__(256, 3) void gemm_qkv_fused(
    const bf16_t* __restrict__ A, const bf16_t* __restrict__ Wt3,
    const float* __restrict__ bq, const float* __restrict__ bk,
    const float* __restrict__ bv, const float* __restrict__ rrb,
    bf16_t* __restrict__ Cq)
{
    __shared__ bf16_t As[128 * 64];
    __shared__ bf16_t Bs[128 * 64];
    const int tid = threadIdx.x;
    const int w = tid >> 6, lane = tid & 63;
    const int quad = lane >> 4, l16 = lane & 15;
    const int bn = blockIdx.x * 128;
    const int bm = blockIdx.y * 128;
    const int proj = bn >> 10;
    const int vswap = (proj == 2);

    const int srow = tid >> 3;
    const int scg  = (tid & 7) ^ ((tid >> 3) & 7);
    const bf16_t* Ab = A   + (size_t)(bm + srow) * KSPLIT + scg * 8;
    const bf16_t* Bb = Wt3 + (size_t)(bn + srow) * KSPLIT + scg * 8;

    f32x4 acc[2][8];
#pragma unroll
    for (int i = 0; i < 2; i++)
#pragma unroll
        for (int j = 0; j < 8; j++) {
            acc[i][j][0] = 0.f; acc[i][j][1] = 0.f;
            acc[i][j][2] = 0.f; acc[i][j][3] = 0.f;
        }

    const bf16_t* P1 = vswap ? Bs : As;
    const bf16_t* P2 = vswap ? As : Bs;

    for (int k0 = 0; k0 < KSPLIT; k0 += 64) {
#pragma unroll
        for (int j = 0; j < 4; j++) {
            load_lds16(Ab + (size_t)j * 32 * KSPLIT + k0, &As[j * 2048 + w * 512]);
            load_lds16(Bb + (size_t)j * 32 * KSPLIT + k0, &Bs[j * 2048 + w * 512]);
        }
        __syncthreads();
        bf16x8 af[2][2];
#pragma unroll
        for (int mt = 0; mt < 2; mt++) {
            int r = w * 32 + mt * 16 + l16, rx = r & 7;
            int c0 = (quad ^ rx);
            af[mt][0] = *(const bf16x8*)&P1[r * 64 + c0 * 8];
            af[mt][1] = *(const bf16x8*)&P1[r * 64 + (c0 ^ 4) * 8];
        }
#pragma unroll
        for (int nt = 0; nt < 8; nt++) {
            int r = nt * 16 + l16, rx = r & 7;
            int c0 = (quad ^ rx);
            bf16x8 b0 = *(const bf16x8*)&P2[r * 64 + c0 * 8];
            bf16x8 b1 = *(const bf16x8*)&P2[r * 64 + (c0 ^ 4) * 8];
#pragma unroll
            for (int mt = 0; mt < 2; mt++) {
                acc[mt][nt] = __builtin_amdgcn_mfma_f32_16x16x32_bf16(af[mt][0], b0, acc[mt][nt], 0, 0, 0);
                acc[mt][nt] = __builtin_amdgcn_mfma_f32_16x16x32_bf16(af[mt][1], b1, acc[mt][nt], 0, 0, 0);
            }
        }
        __syncthreads();
    }

#pragma unroll
    for (int mt = 0; mt < 2; mt++)
#pragma unroll
        for (int nt = 0; nt < 8; nt++)
#pragma unroll
            for (int r4 = 0; r4 < 4; r4++) {
                int rowp = w * 32 + mt * 16 + quad * 4 + r4;
                int colp = nt * 16 + l16;
                float v = acc[mt][nt][r4];
                if (!vswap) {
                    int m = bm + rowp, nloc = (bn & 1023) + colp;
                    v += (proj == 0) ? (bq[nloc] + rrb[nloc]) : bk[nloc];
                    int bb = m >> 11, s = m & (SEQ - 1);
                    int nh = nloc >> 6, d = nloc & 63;
                    Cq[(size_t)proj * HEADSZ + (((size_t)(bb * NHEAD + nh) * SEQ + s) * DHEAD) + d] = (bf16_t)v;
                } else {
                    int nloc = (bn & 1023) + rowp, m = bm + colp;
                    v += bv[nloc];
                    int bb = m >> 11, s = m & (SEQ - 1);
                    int nh = nloc >> 6, d = nloc & 63;
                    int j = s & 127;
                    int s2 = (s & ~127) | (((j & 15) << 3) | (j >> 4));  // key perm
                    Cq[(size_t)2 * HEADSZ + (((size_t)(bb * NHEAD + nh) * DHEAD + d) * SEQ) + s2] = (bf16_t)v;
                }
            }
}

// ---------------- R projection (single, row layout) -------------------------
__global__ __launch_bounds__(256, 3) void gemm_split_mfma(
    const bf16_t* __restrict__ A, const bf16_t* __restrict__ Bw,
    bf16_t* __restrict__ C)
{
    __shared__ bf16_t As[128 * 64];
    __shared__ bf16_t Bs[128 * 64];
    const int tid = threadIdx.x;
    const int w = tid >> 6, lane = tid & 63;
    const int quad = lane >> 4, l16 = lane & 15;
    const int bn = blockIdx.x * 128;
    const int bm = blockIdx.y * 128;
    const int srow = tid >> 3;
    const int scg  = (tid & 7) ^ ((tid >> 3) & 7);
    const bf16_t* Ab = A  + (size_t)(bm + srow) * KSPLIT + scg * 8;
    const bf16_t* Bb = Bw + (size_t)(bn + srow) * KSPLIT + scg * 8;

    f32x4 acc[2][8];
#pragma unroll
    for (int i = 0; i < 2; i++)
#pragma unroll
        for (int j = 0; j < 8; j++) {
            acc[i][j][0] = 0.f; acc[i][j][1] = 0.f;
            acc[i][j][2] = 0.f; acc[i][j][3] = 0.f;
        }

    for (int k0 = 0; k0 < KSPLIT; k0 += 64) {
#pragma unroll
        for (int j = 0; j < 4; j++) {
            load_lds16(Ab + (size_t)j * 32 * KSPLIT + k0, &As[j * 2048 + w * 512]);
            load_lds16(Bb + (size_t)j * 32 * KSPLIT + k0, &Bs[j * 2048 + w * 512]);
        }
        __syncthreads();
        bf16x8 af[2][2];
#pragma unroll
        for (int mt = 0; mt < 2; mt++) {
            int r = w * 32 + mt * 16 + l16, rx = r & 7;
            int c0 = (quad ^ rx);
            af[mt][0] = *(const bf16x8*)&As[r * 64 + c0 * 8];
            af[mt][1] = *(const bf16x8*)&As[r * 64 + (c0 ^ 4) * 8];
        }
#pragma unroll
        for (int nt = 0; nt < 8; nt++) {
            int r = nt * 16 + l16, rx = r & 7;
            int c0 = (quad ^ rx);
            bf16x8 b0 = *(const bf16x8*)&Bs[r * 64 + c0 * 8];
            bf16x8 b1 = *(const bf16x8*)&Bs[r * 64 + (c0 ^ 4) * 8];
#pragma unroll
            for (int mt = 0; mt < 2; mt++) {
                acc[mt][nt] = __builtin_amdgcn_mfma_f32_16x16x32_bf16(af[mt][0], b0, acc[mt][nt], 0, 0, 0);
                acc[mt][nt] = __builtin_amdgcn_mfma_f32_16x16x32_bf16(af[mt][1], b1, acc[mt][nt], 0, 0, 0);
            }
        }
        __syncthreads();
    }
#pragma unroll
    for (int mt = 0; mt < 2; mt++)
#pragma unroll
        for (int nt = 0; nt < 8; nt++)
#pragma unroll
            for (int r4 = 0; r4 < 4; r4++) {
                int rowp = w * 32 + mt * 16 + quad * 4 + r4;
                int colp = nt * 16 + l16;
                int s = bm + rowp, n = bn + colp;
                int nh = n >> 6, d = n & 63;
                C[(((size_t)nh * SEQ + s) * DHEAD) + d] = (bf16_t)acc[mt][nt][r4];
            }
}

// ---------------- prep 3: dcorr[b,n,s] = (rwb-rrb) . K[b,n,s,:] -------------
__global__ __launch_bounds__(256) void dcorr_kernel(
    const bf16_t* __restrict__ Kh, const float* __restrict__ rwb,
    const float* __restrict__ rrb, float* __restrict__ dc)
{
    int g = blockIdx.x * 256 + threadIdx.x;
    int bn = g >> 11;
    int n = bn & (NHEAD - 1);
    const bf16_t* kr = Kh + (size_t)g * DHEAD;
    float a = 0.f;
#pragma unroll
    for (int c8 = 0; c8 < 8; c8++) {
        bf16x8 kv = *(const bf16x8*)(kr + c8 * 8);
#pragma unroll
        for (int e = 0; e < 8; e++) {
            int d = c8 * 8 + e;
            a = fmaf(rwb[n * DHEAD + d] - rrb[n * DHEAD + d], (float)kv[e], a);
        }
    }
    dc[g] = a;
}

// ---------------- MFMA flash rel-attention v5 --------------------------------
// Round-5 register profile (band MFMA uses unshifted aq frags only). Per-tile
// block-uniform specialization: lstar = 64+i0-j0.
//   mixed (0<lstar<191, exactly 1/16 tiles): per-element gather, B4 barrier.
//   uniform: gather ip = il0+r+shift (shift = lstar<=0), const-offset reads.
//   bd64 only when lstar<127 (col 64 unread otherwise).
//   B4 skipped when lstar>=191 (all band reads wave-local).
// P stored via b128 writes in key-permuted layout matching permuted V.
__global__ __launch_bounds__(256, 2) void rel_attn_mfma5(
    const bf16_t* __restrict__ Qh, const bf16_t* __restrict__ Kh,
    const bf16_t* __restrict__ Vth, const bf16_t* __restrict__ Rkh,
    const float* __restrict__ dcorr, const bf16_t* __restrict__ zp,
    float* __restrict__ Out)
{
    __shared__ bf16_t qs[65 * 64];      // swizzled, stride 64
    __shared__ bf16_t ktP[64 * LDP];    // kt[128*64] U P[64*136]
    __shared__ bf16_t vt[64 * 128];     // [d][key-pos], swizzled (mask 15)
    __shared__ bf16_t rkb[192 * LDBT];  // rkc[192*64] U bandT[192*68]
    __shared__ float dco[TK2];

    const int tid = threadIdx.x;
    const int w = tid >> 6, lane = tid & 63;
    const int quad = lane >> 4, l16 = lane & 15;
    const int i0 = blockIdx.x * TQ;
    const int n = blockIdx.y, b = blockIdx.z;

    const bf16_t* Qb = Qh + ((size_t)(b * NHEAD + n) * SEQ + i0) * DHEAD;
    const bf16_t* Kb = Kh + (size_t)(b * NHEAD + n) * SEQ * DHEAD;
    const bf16_t* Vb = Vth + (size_t)(b * NHEAD + n) * DHEAD * SEQ;
    const bf16_t* Rb = Rkh + (size_t)n * SEQ * DHEAD;
    const float*  Db = dcorr + (size_t)(b * NHEAD + n) * SEQ;

    // stage qs (rows i0..i0+64; row 64 zero if OOB), source-chunk swizzle
    for (int idx = tid; idx < 65 * 8; idx += 256) {
        int row = idx >> 3, p = idx & 7;
        int g = p ^ (row & 7);
        uint4 val = make_uint4(0, 0, 0, 0);
        if (i0 + row < SEQ) val = *(const uint4*)(Qb + row * DHEAD + g * 8);
        *(uint4*)&qs[row * 64 + p * 8] = val;
    }
    __syncthreads();

    // hoisted A-fragments (qs static)
    const int rq = 16 * w + l16;
    const int cq0 = quad ^ (rq & 7);
    const bf16x8 aq0 = *(const bf16x8*)&qs[rq * 64 + cq0 * 8];
    const bf16x8 aq1 = *(const bf16x8*)&qs[rq * 64 + (cq0 ^ 4) * 8];

    f32x4 o[4];
    float mprev[4], lsum[4];
#pragma unroll
    for (int t = 0; t < 4; t++) {
        o[t][0] = 0.f; o[t][1] = 0.f; o[t][2] = 0.f; o[t][3] = 0.f;
        mprev[t] = -3.0e38f; lsum[t] = 0.f;
    }
    const float C1 = 0.18033688f;   // 0.125 * log2(e)

    for (int j0 = 0; j0 < SEQ; j0 += TK2) {
        const int lstar = 64 + i0 - j0;              // rr == SEQ at l == lstar
        const bool mixed = (lstar > 0) && (lstar < NW2);
        const bool needB4 = (lstar < NW2);
        const bool needBd64 = (lstar < 127);

        __syncthreads();                             // B1: prev consumers done
#pragma unroll
        for (int t = 0; t < 4; t++) {
            int r0 = (w + 4 * t) * 8;
            int row = r0 + (lane >> 3);
            int gch = (lane & 7) ^ (row & 7);
            load_lds16(Kb + (size_t)(j0 + row) * DHEAD + gch * 8, &ktP[r0 * 64]);
        }
#pragma unroll
        for (int t = 0; t < 4; t++) {
            int d0 = (w + 4 * t) * 4;
            int d = d0 + (lane >> 4);
            int gch = (lane & 15) ^ (d & 15);
            load_lds16(Vb + (size_t)d * SEQ + j0 + gch * 8, &vt[d0 * 128]);
        }
        const int base1 = SEQ + j0 - i0 - TQ;
#pragma unroll
        for (int t = 0; t < 6; t++) {
            int l0 = (w + 4 * t) * 8;
            int l = l0 + (lane >> 3);
            int rr = base1 + l;
            const bf16_t* rp = (rr < SEQ) ? (Rb + (size_t)rr * DHEAD)
                             : (rr > SEQ) ? (Rb + (size_t)(rr - SEQ - 1) * DHEAD) : zp;
            int gch = (lane & 7) ^ (l & 7);
            load_lds16(rp + gch * 8, &rkb[l0 * 64]);
        }
        if (tid < 32) load_lds16(Db + j0 + tid * 4, dco);
        __syncthreads();                             // B2: staging visible

        // ---- MFMA: AC (8x2) + band (12x2) ----
        f32x4 sac[8];
#pragma unroll
        for (int nt = 0; nt < 8; nt++) {
            int r = nt * 16 + l16;
            int c0 = quad ^ (r & 7);
            bf16x8 b0 = *(const bf16x8*)&ktP[r * 64 + c0 * 8];
            bf16x8 b1 = *(const bf16x8*)&ktP[r * 64 + (c0 ^ 4) * 8];
            f32x4 c; c[0] = 0.f; c[1] = 0.f; c[2] = 0.f; c[3] = 0.f;
            c = __builtin_amdgcn_mfma_f32_16x16x32_bf16(aq0, b0, c, 0, 0, 0);
            c = __builtin_amdgcn_mfma_f32_16x16x32_bf16(aq1, b1, c, 0, 0, 0);
            sac[nt] = c;
        }
        f32x4 bdc[12];
#pragma unroll
        for (int lt = 0; lt < 12; lt++) {
            int l = lt * 16 + l16;
            int c0 = quad ^ (l & 7);
            bf16x8 b0 = *(const bf16x8*)&rkb[l * 64 + c0 * 8];
            bf16x8 b1 = *(const bf16x8*)&rkb[l * 64 + (c0 ^ 4) * 8];
            f32x4 c; c[0] = 0.f; c[1] = 0.f; c[2] = 0.f; c[3] = 0.f;
            c = __builtin_amdgcn_mfma_f32_16x16x32_bf16(aq0, b0, c, 0, 0, 0);
            c = __builtin_amdgcn_mfma_f32_16x16x32_bf16(aq1, b1, c, 0, 0, 0);
            bdc[lt] = c;
        }
        // band col-64 source (q row 64): only when some il=63 element is case-2
        float bd64 = 0.f;
        if (needBd64 && w >= 2) {
            int l = (w - 2) * 64 + lane;
            int lx = l & 7;
#pragma unroll
            for (int c = 0; c < 8; c++) {
                bf16x8 qv = *(const bf16x8*)&qs[64 * 64 + c * 8];
                bf16x8 rv = *(const bf16x8*)&rkb[l * 64 + (c ^ lx) * 8];
#pragma unroll
                for (int e = 0; e < 8; e++) bd64 = fmaf((float)qv[e], (float)rv[e], bd64);
            }
        }
        __syncthreads();                             // B3: kt/rkc frag reads done

        // ---- band store, transposed: bandT[l][i'] (b64 writes) ----
#pragma unroll
        for (int lt = 0; lt < 12; lt++) {
            int l = lt * 16 + l16;
            bf16x4 pk;
#pragma unroll
            for (int r = 0; r < 4; r++) pk[r] = (bf16_t)bdc[lt][r];
            *(bf16x4*)&rkb[l * LDBT + 16 * w + quad * 4] = pk;
        }
        if (needBd64 && w >= 2) rkb[((w - 2) * 64 + lane) * LDBT + 64] = (bf16_t)bd64;
        if (needB4) __syncthreads();                 // B4: cross-wave band visible

        // ---- gather + assemble + online softmax (exp2) ----
        float sv[8][4];
        if (mixed) {
#pragma unroll
            for (int nt = 0; nt < 8; nt++) {
                float dcv = dco[nt * 16 + l16];
#pragma unroll
                for (int r = 0; r < 4; r++) {
                    int il = 16 * w + quad * 4 + r;
                    int jl = nt * 16 + l16;
                    int l = jl + (TQ - 1) - il;
                    int rr = base1 + l;
                    int ip = il + (rr > SEQ ? 1 : 0);
                    float bd = (float)rkb[l * LDBT + ip];
                    sv[nt][r] = sac[nt][r] + dcv + bd;
                }
            }
        } else {
            const int shift = (lstar <= 0) ? 1 : 0;  // block-uniform case bit
            const int il0 = 16 * w + quad * 4;
            const int base = (l16 + (TQ - 1) - il0) * LDBT + il0 + shift;
#pragma unroll
            for (int nt = 0; nt < 8; nt++) {
                float dcv = dco[nt * 16 + l16];
#pragma unroll
                for (int r = 0; r < 4; r++) {
                    float bd = (float)rkb[base + nt * 16 * LDBT - r * (LDBT - 1)];
                    sv[nt][r] = sac[nt][r] + dcv + bd;
                }
            }
        }
#pragma unroll
        for (int r = 0; r < 4; r++) {
            float m = sv[0][r];
#pragma unroll
            for (int nt = 1; nt < 8; nt++) m = fmaxf(m, sv[nt][r]);
            m = fmaxf(m, __shfl_xor(m, 1));
            m = fmaxf(m, __shfl_xor(m, 2));
            m = fmaxf(m, __shfl_xor(m, 4));
            m = fmaxf(m, __shfl_xor(m, 8));
            float mnew = fmaxf(mprev[r], m);
            float alpha = exp2f((mprev[r] - mnew) * C1);
            float s = 0.f;
#pragma unroll
            for (int nt = 0; nt < 8; nt++) {
                sv[nt][r] = exp2f((sv[nt][r] - mnew) * C1);
                s += sv[nt][r];
            }
            s += __shfl_xor(s, 1); s += __shfl_xor(s, 2);
            s += __shfl_xor(s, 4); s += __shfl_xor(s, 8);
            lsum[r] = lsum[r] * alpha + s;
            mprev[r] = mnew;
#pragma unroll
            for (int nt = 0; nt < 4; nt++) o[nt][r] *= alpha;
        }

        // ---- P store: permuted layout pos p = l16*8 + nt -> 4 b128 writes ----
        // (kt region; kt reads done at B3; rows wave-local)
#pragma unroll
        for (int r = 0; r < 4; r++) {
            bf16x8 px;
#pragma unroll
            for (int nt = 0; nt < 8; nt++) px[nt] = (bf16_t)sv[nt][r];
            *(bf16x8*)&ktP[(16 * w + quad * 4 + r) * LDP + l16 * 8] = px;
        }

        // ---- PV (wave-local P rows, no barrier; V pre-permuted to match) ----
        bf16x8 pa[4];
#pragma unroll
        for (int c = 0; c < 4; c++)
            pa[c] = *(const bf16x8*)&ktP[(16 * w + l16) * LDP + c * 32 + quad * 8];
#pragma unroll
        for (int nt = 0; nt < 4; nt++) {
#pragma unroll
            for (int c = 0; c < 4; c++) {
                int dv = nt * 16 + l16;
                int gch = (4 * c + quad) ^ (dv & 15);
                bf16x8 vb = *(const bf16x8*)&vt[dv * 128 + gch * 8];
                o[nt] = __builtin_amdgcn_mfma_f32_16x16x32_bf16(pa[c], vb, o[nt], 0, 0, 0);
            }
        }
    }

    float inv[4];
#pragma unroll
    for (int r = 0; r < 4; r++) inv[r] = 1.f / lsum[r];
#pragma unroll
    for (int nt = 0; nt < 4; nt++)
#pragma unroll
        for (int r = 0; r < 4; r++) {
            int gi = i0 + 16 * w + quad * 4 + r;
            Out[(size_t)(b * SEQ + gi) * HID + n * DHEAD + nt * 16 + l16] = o[nt][r] * inv[r];
        }
}

extern "C" void kernel_launch(void* const* d_in, const int* in_sizes, int n_in,
                              void* d_out, int out_size, void* d_ws, size_t ws_size,
                              hipStream_t stream) {
    const float* hs  = (const float*)d_in[0];
    const float* r   = (const float*)d_in[1];
    const float* rwb = (const float*)d_in[2];
    const float* rrb = (const float*)d_in[3];
    const float* Wq  = (const float*)d_in[4];
    const float* bq  = (const float*)d_in[5];
    const float* Wk  = (const float*)d_in[6];
    const float* bk  = (const float*)d_in[7];
    const float* Wv  = (const float*)d_in[8];
    const float* bv  = (const float*)d_in[9];
    const float* Wr  = (const float*)d_in[10];

    bf16_t* ws0 = (bf16_t*)d_ws;
    bf16_t* hsS = ws0;
    bf16_t* Wt3 = ws0 + (size_t)4096 * KSPLIT;
    bf16_t* Qh  = Wt3 + (size_t)3072 * KSPLIT;
    bf16_t* Kh  = Qh + HEADSZ;
    bf16_t* Vh  = Kh + HEADSZ;
    bf16_t* Rh  = Vh + HEADSZ;
    bf16_t* rS  = ws0;                                    // reuses hsS region
    bf16_t* WtR = ws0 + (size_t)2048 * KSPLIT;            // reuses hsS region
    float*  dcG = (float*)(ws0 + (size_t)3072 * KSPLIT);  // reuses hsS region
    bf16_t* zp  = ws0 + (size_t)3072 * KSPLIT + 2 * BATCH * NHEAD * SEQ;

    dim3 blk(256);

    split_interleave<<<4096, blk, 0, stream>>>(hs, hsS, (BATCH * SEQ * HID) / 4);
    transpose_split3<<<dim3(16, 16, 3), blk, 0, stream>>>(Wq, Wk, Wv, Wt3);
    gemm_qkv_fused<<<dim3(24, 32), blk, 0, stream>>>(hsS, Wt3, bq, bk, bv, rrb, Qh);

    split_interleave<<<2048, blk, 0, stream>>>(r, rS, (SEQ * HID) / 4);
    transpose_split<<<dim3(16, 16), blk, 0, stream>>>(Wr, WtR);
    gemm_split_mfma<<<dim3(8, 16), blk, 0, stream>>>(rS, WtR, Rh);

    dcorr_kernel<<<(BATCH * NHEAD * SEQ) / 256, blk, 0, stream>>>(Kh, rwb, rrb, dcG);
    hipMemsetAsync(zp, 0, 256, stream);

    rel_attn_mfma5<<<dim3(SEQ / TQ, NHEAD, BATCH), blk, 0, stream>>>(
        Qh, Kh, Vh, Rh, dcG, zp, (float*)d_out);
}